// Round 12
// baseline (8868.098 us; speedup 1.0000x reference)
//
#include <hip/hip_runtime.h>
#include <hip/hip_bf16.h>

// Sizes from the reference
#define NSEQ   32
#define SEQLEN 256
#define NB     16    // batch
#define NIN    32
#define NH     256
#define G4     1024  // 4*H

#define PROBE_T 2    // steps using dual-publish + probe before consensus

typedef __attribute__((ext_vector_type(8))) short bf16x8;
typedef __attribute__((ext_vector_type(4))) float f32x4;
typedef unsigned long long ull;

__device__ __forceinline__ unsigned short f2bf(float f) {
    union { float f; unsigned u; } v; v.f = f;
    unsigned u = v.u;
    return (unsigned short)((u + 0x7FFFu + ((u >> 16) & 1u)) >> 16);  // RNE
}
__device__ __forceinline__ float bf2f(unsigned short u) {
    union { unsigned u; float f; } v; v.u = ((unsigned)u) << 16; return v.f;
}
__device__ __forceinline__ float sigf(float x) { return 1.0f / (1.0f + __expf(-x)); }
__device__ __forceinline__ float tanhfast(float x) { return 1.0f - 2.0f / (__expf(2.0f * x) + 1.0f); }

// ---------------- Prologue: pack weights into MFMA B-fragment layout ----------------
__global__ void pack_w1(const float* __restrict__ Wih, const float* __restrict__ Whh,
                        unsigned short* __restrict__ Bp) {
    int idx = blockIdx.x * blockDim.x + threadIdx.x;
    if (idx >= 2 * 64 * 9 * 64) return;
    int fl   = idx / (64 * 9 * 64);
    int rem  = idx % (64 * 9 * 64);
    int tile = rem / (9 * 64);
    int kk   = (rem / 64) % 9;
    int l    = rem & 63;
    int n    = tile * 16 + (l & 15);
    int k0   = kk * 32 + (l >> 4) * 8;
    unsigned short* dst = Bp + (size_t)idx * 8;
#pragma unroll
    for (int j = 0; j < 8; ++j) {
        int k = k0 + j;
        float v = (k < NH) ? Whh[((size_t)fl * G4 + n) * NH + k]
                           : Wih[((size_t)fl * G4 + n) * NIN + (k - NH)];
        dst[j] = f2bf(v);
    }
}

__global__ void pack_w2(const float* __restrict__ Wih, const float* __restrict__ Whh,
                        unsigned short* __restrict__ Bp) {
    int idx = blockIdx.x * blockDim.x + threadIdx.x;
    if (idx >= 64 * 16 * 64) return;
    int tile = idx / (16 * 64);
    int kk   = (idx / 64) % 16;
    int l    = idx & 63;
    int n    = tile * 16 + (l & 15);
    int k0   = kk * 32 + (l >> 4) * 8;
    unsigned short* dst = Bp + (size_t)idx * 8;
#pragma unroll
    for (int j = 0; j < 8; ++j) {
        int k = k0 + j;
        float v = (k < NH) ? Whh[(size_t)n * NH + k] : Wih[(size_t)n * NH + (k - NH)];
        dst[j] = f2bf(v);
    }
}

// ---------------- Layer 1: R7 skeleton + remote-direct-to-reg + x prefetch d2 ----------------
// bid = j*32 + s (j=0..3) -> 4 blocks of seq s on XCD s%8 (heuristic; runtime-validated).
// Wave w (16): gate g=w>>2, colgroup cg=w&3, tile=g*16+j*4+cg; wreg[9] (36 VGPR,
// ALL indices compile-time -- rule #20).
// Fast path: own kks {2j,2j+1} + x from LDS; 6 remote kks read straight into MFMA
// A-fragments via scalar volatile loads (tagged, spin-checked), staged in 2 halves.
#define STRA 320                   // Ash row stride in ushorts; 640B = 5*128B
#define ASH_BYTES (NB * STRA * 2)  // 10240 per buffer

__device__ __forceinline__ unsigned aoff(int row, int col) {  // swizzled byte offset
    return (((unsigned)(row * STRA + col)) * 2u) ^ (((unsigned)row & 7u) << 4);
}

// 8 scalar volatile dword loads (L1-bypass, L2-coherent) -- proven class (R6-R8).
__device__ __forceinline__ void vload8_sc0(const unsigned* p, unsigned (&d)[8]) {
    volatile const unsigned* vp = p;
#pragma unroll
    for (int i = 0; i < 8; ++i) d[i] = vp[i];
}

#define LDSFRAG(kk) (*(const bf16x8*)(Ash[cur] + aoff(lr, (kk) * 32 + kg * 8)))
// spin until fragment's 8 tagged words show tag tgc, repack hi-halves, MFMA (literal kk!)
#define SPIN_MFMA(rq, kk, A) { \
    for (;;) { bool okk = true; \
        _Pragma("unroll") for (int e = 0; e < 8; ++e) okk &= ((rq[e] & 0xFFFFu) == tgc); \
        if (okk) break; \
        vload8_sc0(rowFc + fo + (kk) * 32, rq); } \
    union { bf16x8 v; unsigned d[4]; } fa_; \
    fa_.d[0] = (rq[0] >> 16) | (rq[1] & 0xFFFF0000u); \
    fa_.d[1] = (rq[2] >> 16) | (rq[3] & 0xFFFF0000u); \
    fa_.d[2] = (rq[4] >> 16) | (rq[5] & 0xFFFF0000u); \
    fa_.d[3] = (rq[6] >> 16) | (rq[7] & 0xFFFF0000u); \
    A = __builtin_amdgcn_mfma_f32_16x16x32_bf16(fa_.v, wreg[kk], A, 0, 0, 0); }
#define LDS_MFMA(kk, A) \
    A = __builtin_amdgcn_mfma_f32_16x16x32_bf16(LDSFRAG(kk), wreg[kk], A, 0, 0, 0);

__global__ __launch_bounds__(1024) void lstm_layer1(
    const float* __restrict__ x, const int* __restrict__ flags,
    const float* __restrict__ bih, const float* __restrict__ bhh,
    const unsigned short* __restrict__ Bp_all,
    unsigned short* __restrict__ h1bf,
    unsigned* __restrict__ hxS,    // [NSEQ][2][NB][256] tagged uints (MALL path)
    unsigned* __restrict__ hxF,    // [NSEQ][2][NB][256] tagged uints (L2 path)
    unsigned* __restrict__ vslot)  // [NSEQ][4] verdicts
{
    __shared__ __align__(16) unsigned char Ash[2][ASH_BYTES];  // [h(256)|x(32)] swizzled
    __shared__ float gate[4][64][17];
    __shared__ int s_fail, s_groupF;

    const int bid = blockIdx.x;
    const int s   = bid & 31;
    const int j   = bid >> 5;       // 0..3
    const int tid = threadIdx.x;
    const int w = tid >> 6, l = tid & 63, lr = l & 15, kg = l >> 4;
    const int g = w >> 2, cg = w & 3;
    const int fl = flags[s];
    const int tile = g * 16 + j * 4 + cg;
    const unsigned short* Bp = Bp_all + (size_t)fl * (64 * 9 * 64 * 8);

    bf16x8 wreg[9];
#pragma unroll
    for (int kk = 0; kk < 9; ++kk)
        wreg[kk] = *(const bf16x8*)(Bp + ((size_t)(tile * 9 + kk) * 64 + l) * 8);

    const int grow = tile * 16 + lr;
    const float bias = bih[fl * G4 + grow] + bhh[fl * G4 + grow];

    const int pb = tid >> 6, pc = tid & 63;   // epilogue/post/readback: (batch, local col)
    const int o0 = (((j + 1) & 3) << 6) + pc; // the 3 peer column slots (slow path)
    const int o1 = (((j + 2) & 3) << 6) + pc;
    const int o2 = (((j + 3) & 3) << 6) + pc;
    const int xb = tid >> 5, xk = tid & 31;   // x staging (tid < 512)
    const int fo = lr * 256 + kg * 8;         // fast-path fragment dword offset (+kk*32)
    float cst = 0.f;
    int mode = 0;       // sticky per-thread (non-consensus path): 0 probe, 1 F, 2 S
    bool groupF = false;

    unsigned* hxSs = hxS + (size_t)s * (2 * NB * 256);
    unsigned* hxFs = hxF + (size_t)s * (2 * NB * 256);

    if (tid == 0) { s_fail = 0; s_groupF = 0; }
    for (int i = tid * 4; i < 2 * ASH_BYTES; i += 1024 * 4)
        *(unsigned*)(&Ash[0][0] + i) = 0u;
    __syncthreads();
    if (tid < NB * NIN)
        *(unsigned short*)(&Ash[0][0] + aoff(xb, NH + xk)) =
            f2bf(x[(((size_t)s * SEQLEN) * NB + xb) * NIN + xk]);
    __syncthreads();

    // x pipeline: xp1 holds x for step t+1 (loaded >=1 full step ahead)
    float xp1 = 0.f;
    if (tid < NB * NIN)
        xp1 = x[(((size_t)s * SEQLEN + 1) * NB + xb) * NIN + xk];

    for (int t = 0; t < SEQLEN; ++t) {
        const int cur = t & 1, nxt = cur ^ 1;
        float xp2 = 0.f;
        if (t + 2 < SEQLEN && tid < NB * NIN)
            xp2 = x[(((size_t)s * SEQLEN + t + 2) * NB + xb) * NIN + xk];

        if (groupF) {
            // ================= FAST PATH =================
            const unsigned tgc = (unsigned)t;            // gen-t tag
            const unsigned* rowFc = hxFs + cur * NB * 256;

            // half A: issue remote loads for kk 0..3 (own pair skipped, uniform branch)
            unsigned r0[8], r1[8], r2[8], r3[8];
            if (j != 0) { vload8_sc0(rowFc + fo +  0, r0); vload8_sc0(rowFc + fo + 32, r1); }
            if (j != 1) { vload8_sc0(rowFc + fo + 64, r2); vload8_sc0(rowFc + fo + 96, r3); }

            f32x4 acc  = {bias, bias, bias, bias};
            f32x4 accB = {0.f, 0.f, 0.f, 0.f};
            // chain1: kk 8 (x, always LDS) then 0..3
            LDS_MFMA(8, acc);
            if (j == 0) { LDS_MFMA(0, acc); LDS_MFMA(1, acc); }
            else        { SPIN_MFMA(r0, 0, acc); SPIN_MFMA(r1, 1, acc); }
            if (j == 1) { LDS_MFMA(2, acc); LDS_MFMA(3, acc); }
            else        { SPIN_MFMA(r2, 2, acc); SPIN_MFMA(r3, 3, acc); }

            // half B: issue remote loads for kk 4..7, then chain2
            unsigned r4[8], r5[8], r6[8], r7[8];
            if (j != 2) { vload8_sc0(rowFc + fo + 128, r4); vload8_sc0(rowFc + fo + 160, r5); }
            if (j != 3) { vload8_sc0(rowFc + fo + 192, r6); vload8_sc0(rowFc + fo + 224, r7); }
            if (j == 2) { LDS_MFMA(4, accB); LDS_MFMA(5, accB); }
            else        { SPIN_MFMA(r4, 4, accB); SPIN_MFMA(r5, 5, accB); }
            if (j == 3) { LDS_MFMA(6, accB); LDS_MFMA(7, accB); }
            else        { SPIN_MFMA(r6, 6, accB); SPIN_MFMA(r7, 7, accB); }

#pragma unroll
            for (int r = 0; r < 4; ++r)
                gate[g][cg * 16 + lr][kg * 4 + r] = acc[r] + accB[r];
            __syncthreads();  // B1

            // epilogue: 1 thread = 1 (batch, col); post F + own LDS + x staging
            float ig = gate[0][pc][pb], fg = gate[1][pc][pb];
            float gg = gate[2][pc][pb], og = gate[3][pc][pb];
            float cn = sigf(fg) * cst + sigf(ig) * tanhfast(gg);
            cst = cn;
            unsigned short hb = f2bf(sigf(og) * tanhfast(cn));
            if (t == SEQLEN - 1) {
                h1bf[((size_t)s * NB + pb) * NH + (j << 6) + pc] = hb;
            } else {
                hxFs[(size_t)(nxt * NB + pb) * 256 + (j << 6) + pc] =
                    ((unsigned)hb << 16) | (unsigned)(t + 1);
                *(unsigned short*)(Ash[nxt] + aoff(pb, (j << 6) + pc)) = hb;
                if (tid < NB * NIN)
                    *(unsigned short*)(Ash[nxt] + aoff(xb, NH + xk)) = f2bf(xp1);
            }
            __syncthreads();  // B2
        } else {
            // ================= SLOW PATH (probe t<PROBE_T, or F not validated) =================
            f32x4 acc = {bias, bias, bias, bias};
            f32x4 accB = {0.f, 0.f, 0.f, 0.f};
#pragma unroll
            for (int kk = 0; kk < 5; ++kk) LDS_MFMA(kk, acc);
#pragma unroll
            for (int kk = 5; kk < 9; ++kk) LDS_MFMA(kk, accB);
#pragma unroll
            for (int r = 0; r < 4; ++r)
                gate[g][cg * 16 + lr][kg * 4 + r] = acc[r] + accB[r];
            __syncthreads();  // B1

            float ig = gate[0][pc][pb], fg = gate[1][pc][pb];
            float gg = gate[2][pc][pb], og = gate[3][pc][pb];
            float cn = sigf(fg) * cst + sigf(ig) * tanhfast(gg);
            cst = cn;
            unsigned short hb = f2bf(sigf(og) * tanhfast(cn));

            if (t == SEQLEN - 1) {
                h1bf[((size_t)s * NB + pb) * NH + (j << 6) + pc] = hb;
                __syncthreads();
            } else {
                const unsigned tg = (unsigned)(t + 1);
                unsigned* rowF = hxFs + (size_t)(nxt * NB + pb) * 256;
                unsigned* rowS = hxSs + (size_t)(nxt * NB + pb) * 256;
                volatile const unsigned* F = rowF;
                rowF[(j << 6) + pc] = ((unsigned)hb << 16) | tg;
                if ((t < PROBE_T) || !groupF)
                    __hip_atomic_store(rowS + (j << 6) + pc, ((unsigned)hb << 16) | tg,
                                       __ATOMIC_RELAXED, __HIP_MEMORY_SCOPE_AGENT);
                *(unsigned short*)(Ash[nxt] + aoff(pb, (j << 6) + pc)) = hb;
                if (tid < NB * NIN)
                    *(unsigned short*)(Ash[nxt] + aoff(xb, NH + xk)) = f2bf(xp1);

                unsigned v0 = F[o0], v1 = F[o1], v2 = F[o2];
                bool ok = false;
                if (mode != 2) {
                    int budget = (mode == 0) ? 300 : 4000;
                    while ((v0 & 0xFFFFu) != tg && budget-- > 0) v0 = F[o0];
                    while ((v1 & 0xFFFFu) != tg && budget-- > 0) v1 = F[o1];
                    while ((v2 & 0xFFFFu) != tg && budget-- > 0) v2 = F[o2];
                    ok = ((v0 & 0xFFFFu) == tg) && ((v1 & 0xFFFFu) == tg) && ((v2 & 0xFFFFu) == tg);
                    if (t >= PROBE_T) mode = ok ? 1 : 2;
                }
                if (!ok) {
                    if (t < PROBE_T) s_fail = 1;  // benign race, same value
                    do { v0 = __hip_atomic_load(rowS + o0, __ATOMIC_RELAXED, __HIP_MEMORY_SCOPE_AGENT); } while ((v0 & 0xFFFFu) != tg);
                    do { v1 = __hip_atomic_load(rowS + o1, __ATOMIC_RELAXED, __HIP_MEMORY_SCOPE_AGENT); } while ((v1 & 0xFFFFu) != tg);
                    do { v2 = __hip_atomic_load(rowS + o2, __ATOMIC_RELAXED, __HIP_MEMORY_SCOPE_AGENT); } while ((v2 & 0xFFFFu) != tg);
                }
                *(unsigned short*)(Ash[nxt] + aoff(pb, o0)) = (unsigned short)(v0 >> 16);
                *(unsigned short*)(Ash[nxt] + aoff(pb, o1)) = (unsigned short)(v1 >> 16);
                *(unsigned short*)(Ash[nxt] + aoff(pb, o2)) = (unsigned short)(v2 >> 16);
                __syncthreads();  // B2

                if (t == PROBE_T - 1) {
                    if (tid == 0) {
                        unsigned verdict = (s_fail == 0) ? 2u : 1u;
                        __hip_atomic_store(vslot + s * 4 + j, verdict,
                                           __ATOMIC_RELAXED, __HIP_MEMORY_SCOPE_AGENT);
                        unsigned a0, a1, a2, a3;
                        do {
                            a0 = __hip_atomic_load(vslot + s * 4 + 0, __ATOMIC_RELAXED, __HIP_MEMORY_SCOPE_AGENT);
                            a1 = __hip_atomic_load(vslot + s * 4 + 1, __ATOMIC_RELAXED, __HIP_MEMORY_SCOPE_AGENT);
                            a2 = __hip_atomic_load(vslot + s * 4 + 2, __ATOMIC_RELAXED, __HIP_MEMORY_SCOPE_AGENT);
                            a3 = __hip_atomic_load(vslot + s * 4 + 3, __ATOMIC_RELAXED, __HIP_MEMORY_SCOPE_AGENT);
                        } while (!(a0 && a1 && a2 && a3));
                        s_groupF = (a0 == 2u && a1 == 2u && a2 == 2u && a3 == 2u) ? 1 : 0;
                    }
                    __syncthreads();  // once per kernel
                    groupF = (s_groupF != 0);
                }
            }
        }
        xp1 = xp2;
    }
}

// ---------------- Layer 2: 4 blocks (grid 32, bid%8==0 -> same XCD), 32-step scan ----------------
#define STRA2 520  // 512 data + 8 pad

__global__ __launch_bounds__(1024) void lstm_layer2(
    const unsigned short* __restrict__ h1bf,
    const float* __restrict__ bih2, const float* __restrict__ bhh2,
    const unsigned short* __restrict__ Bp2,
    const float* __restrict__ Wlin, const float* __restrict__ blin,
    float* __restrict__ out,
    unsigned* __restrict__ hx2S,   // [2][NB][256] tagged uints (MALL)
    unsigned* __restrict__ hx2F,   // [2][NB][256] tagged uints (L2)
    unsigned* __restrict__ vslot2) // [4]
{
    const int bid = blockIdx.x;
    if (bid & 7) return;
    const int j = bid >> 3;  // 0..3

    __shared__ __align__(16) unsigned short A_sh[NB * STRA2];  // [h2(256)|h1_s(256)]
    __shared__ float gate[4][64][17];
    __shared__ float red[NB * 16];
    __shared__ int s_fail, s_groupF;

    const int tid = threadIdx.x;
    const int w = tid >> 6, l = tid & 63, lr = l & 15, kg = l >> 4;
    const int g = w >> 2, cg = w & 3;
    const int tile = g * 16 + j * 4 + cg;

    bf16x8 wreg[16];
#pragma unroll
    for (int kk = 0; kk < 16; ++kk)
        wreg[kk] = *(const bf16x8*)(Bp2 + ((size_t)(tile * 16 + kk) * 64 + l) * 8);

    const int grow = tile * 16 + lr;
    const float bias = bih2[grow] + bhh2[grow];
    const int pb = tid >> 6, pc = tid & 63;          // epilogue: 1 col per thread
    float cst = 0.f;
    int mode = 0;
    bool groupF = false;
    const int rb = tid >> 6, rc4 = (tid & 63) * 4;   // h1 staging: 4 cols per thread
    const int q0 = (((j + 1) & 3) << 6) + pc;
    const int q1 = (((j + 2) & 3) << 6) + pc;
    const int q2 = (((j + 3) & 3) << 6) + pc;

    if (tid == 0) { s_fail = 0; s_groupF = 0; }
    for (int i = tid; i < NB * NH; i += 1024)
        A_sh[(i >> 8) * STRA2 + (i & 255)] = 0;
    *(ushort4*)&A_sh[rb * STRA2 + NH + rc4] = *(const ushort4*)&h1bf[(size_t)rb * NH + rc4];
    __syncthreads();

    for (int sq = 0; sq < NSEQ; ++sq) {
        ushort4 pre = {0, 0, 0, 0};
        if (sq + 1 < NSEQ)
            pre = *(const ushort4*)&h1bf[((size_t)(sq + 1) * NB + rb) * NH + rc4];

        f32x4 acc = {bias, bias, bias, bias};
        f32x4 accB = {0.f, 0.f, 0.f, 0.f};
#pragma unroll
        for (int kk = 0; kk < 8; ++kk) {
            bf16x8 a = *(const bf16x8*)&A_sh[lr * STRA2 + kk * 32 + kg * 8];
            acc = __builtin_amdgcn_mfma_f32_16x16x32_bf16(a, wreg[kk], acc, 0, 0, 0);
        }
#pragma unroll
        for (int kk = 8; kk < 16; ++kk) {
            bf16x8 a = *(const bf16x8*)&A_sh[lr * STRA2 + kk * 32 + kg * 8];
            accB = __builtin_amdgcn_mfma_f32_16x16x32_bf16(a, wreg[kk], accB, 0, 0, 0);
        }
#pragma unroll
        for (int r = 0; r < 4; ++r)
            gate[g][cg * 16 + lr][kg * 4 + r] = acc[r] + accB[r];
        __syncthreads();  // B1

        const unsigned tg = (unsigned)(sq + 1);
        const size_t ro = (size_t)((((sq + 1) & 1) * NB + pb) << 8);
        unsigned* rowF = hx2F + ro;
        unsigned* rowS = hx2S + ro;
        volatile const unsigned* F = rowF;
        {
            float ig = gate[0][pc][pb], fg = gate[1][pc][pb];
            float gg = gate[2][pc][pb], og = gate[3][pc][pb];
            float cn = sigf(fg) * cst + sigf(ig) * tanhfast(gg);
            cst = cn;
            float h = sigf(og) * tanhfast(cn);
            unsigned word = ((unsigned)f2bf(h) << 16) | tg;
            A_sh[pb * STRA2 + (j << 6) + pc] = (unsigned short)(word >> 16);
            rowF[(j << 6) + pc] = word;
            if ((sq < PROBE_T) || !groupF)
                __hip_atomic_store(rowS + (j << 6) + pc, word,
                                   __ATOMIC_RELAXED, __HIP_MEMORY_SCOPE_AGENT);
        }
        unsigned v0 = F[q0], v1 = F[q1], v2 = F[q2];
        if (sq + 1 < NSEQ)
            *(ushort4*)&A_sh[rb * STRA2 + NH + rc4] = pre;

        if (groupF) {
            while ((v0 & 0xFFFFu) != tg) v0 = F[q0];
            while ((v1 & 0xFFFFu) != tg) v1 = F[q1];
            while ((v2 & 0xFFFFu) != tg) v2 = F[q2];
        } else {
            bool ok = false;
            if (mode != 2) {
                int budget = (mode == 0) ? 300 : 4000;
                while ((v0 & 0xFFFFu) != tg && budget-- > 0) v0 = F[q0];
                while ((v1 & 0xFFFFu) != tg && budget-- > 0) v1 = F[q1];
                while ((v2 & 0xFFFFu) != tg && budget-- > 0) v2 = F[q2];
                ok = ((v0 & 0xFFFFu) == tg) && ((v1 & 0xFFFFu) == tg) && ((v2 & 0xFFFFu) == tg);
                if (sq >= PROBE_T) mode = ok ? 1 : 2;
            }
            if (!ok) {
                if (sq < PROBE_T) s_fail = 1;
                do { v0 = __hip_atomic_load(rowS + q0, __ATOMIC_RELAXED, __HIP_MEMORY_SCOPE_AGENT); } while ((v0 & 0xFFFFu) != tg);
                do { v1 = __hip_atomic_load(rowS + q1, __ATOMIC_RELAXED, __HIP_MEMORY_SCOPE_AGENT); } while ((v1 & 0xFFFFu) != tg);
                do { v2 = __hip_atomic_load(rowS + q2, __ATOMIC_RELAXED, __HIP_MEMORY_SCOPE_AGENT); } while ((v2 & 0xFFFFu) != tg);
            }
        }
        A_sh[pb * STRA2 + q0] = (unsigned short)(v0 >> 16);
        A_sh[pb * STRA2 + q1] = (unsigned short)(v1 >> 16);
        A_sh[pb * STRA2 + q2] = (unsigned short)(v2 >> 16);
        __syncthreads();  // B2

        if (sq == PROBE_T - 1) {
            if (tid == 0) {
                unsigned verdict = (s_fail == 0) ? 2u : 1u;
                __hip_atomic_store(vslot2 + j, verdict, __ATOMIC_RELAXED, __HIP_MEMORY_SCOPE_AGENT);
                unsigned a0, a1, a2, a3;
                do {
                    a0 = __hip_atomic_load(vslot2 + 0, __ATOMIC_RELAXED, __HIP_MEMORY_SCOPE_AGENT);
                    a1 = __hip_atomic_load(vslot2 + 1, __ATOMIC_RELAXED, __HIP_MEMORY_SCOPE_AGENT);
                    a2 = __hip_atomic_load(vslot2 + 2, __ATOMIC_RELAXED, __HIP_MEMORY_SCOPE_AGENT);
                    a3 = __hip_atomic_load(vslot2 + 3, __ATOMIC_RELAXED, __HIP_MEMORY_SCOPE_AGENT);
                } while (!(a0 && a1 && a2 && a3));
                s_groupF = (a0 == 2u && a1 == 2u && a2 == 2u && a3 == 2u) ? 1 : 0;
            }
            __syncthreads();
            groupF = (s_groupF != 0);
        }
    }

    // final linear + sigmoid, block 0 (A_sh h-part holds full final h2)
    if (j == 0) {
        if (tid < 256) {
            int b = tid >> 4, kc = tid & 15;
            float pacc = 0.f;
#pragma unroll
            for (int k = 0; k < 16; ++k)
                pacc += bf2f(A_sh[b * STRA2 + kc * 16 + k]) * Wlin[kc * 16 + k];
            red[b * 16 + kc] = pacc;
        }
        __syncthreads();
        if (tid < 16) {
            float ssum = blin[0];
#pragma unroll
            for (int kc = 0; kc < 16; ++kc) ssum += red[tid * 16 + kc];
            out[tid] = 1.0f / (1.0f + __expf(-ssum));
        }
    }
}

// ---------------- host ----------------
extern "C" void kernel_launch(void* const* d_in, const int* in_sizes, int n_in,
                              void* d_out, int out_size, void* d_ws, size_t ws_size,
                              hipStream_t stream) {
    const float* x    = (const float*)d_in[0];
    const int*   flg  = (const int*)d_in[1];
    const float* Wih1 = (const float*)d_in[2];
    const float* Whh1 = (const float*)d_in[3];
    const float* bih1 = (const float*)d_in[4];
    const float* bhh1 = (const float*)d_in[5];
    const float* Wih2 = (const float*)d_in[6];
    const float* Whh2 = (const float*)d_in[7];
    const float* bih2 = (const float*)d_in[8];
    const float* bhh2 = (const float*)d_in[9];
    const float* Wlin = (const float*)d_in[10];
    const float* blin = (const float*)d_in[11];
    float* out = (float*)d_out;

    // workspace layout (ushort units; uint regions 4B-aligned)
    unsigned short* ws   = (unsigned short*)d_ws;
    unsigned short* Bp1  = ws;                       // 2*64*9*64*8  = 589824 ush
    unsigned short* Bp2  = Bp1 + 589824;             // 64*16*64*8   = 524288 ush
    unsigned short* h1bf = Bp2 + 524288;             // 32*16*256    = 131072 ush
    unsigned*       hxS1 = (unsigned*)(h1bf + 131072);  // 262144 uints
    unsigned*       hxF1 = hxS1 + 262144;               // 262144 uints
    unsigned*       hx2S = hxF1 + 262144;               // 8192 uints
    unsigned*       hx2F = hx2S + 8192;                 // 8192 uints
    unsigned*       vs1  = hx2F + 8192;                 // 128 uints
    unsigned*       vs2  = vs1 + 128;                   // 4 uints
    // total ~= 4.65 MB

    // invalidate all exchange tags + verdicts for this launch (captured in graph)
    (void)hipMemsetAsync(hxS1, 0, (size_t)(262144 * 2 + 8192 * 2 + 132) * 4, stream);

    pack_w1<<<dim3(288), dim3(256), 0, stream>>>(Wih1, Whh1, Bp1);
    pack_w2<<<dim3(256), dim3(256), 0, stream>>>(Wih2, Whh2, Bp2);
    lstm_layer1<<<dim3(128), dim3(1024), 0, stream>>>(x, flg, bih1, bhh1, Bp1, h1bf,
                                                      hxS1, hxF1, vs1);
    lstm_layer2<<<dim3(32), dim3(1024), 0, stream>>>(h1bf, bih2, bhh2, Bp2, Wlin, blin, out,
                                                     hx2S, hx2F, vs2);
}

// Round 13
// 770.283 us; speedup vs baseline: 11.5128x; 11.5128x over previous
//
#include <hip/hip_runtime.h>
#include <hip/hip_bf16.h>

// Sizes from the reference
#define NSEQ   32
#define SEQLEN 256
#define NB     16    // batch
#define NIN    32
#define NH     256
#define G4     1024  // 4*H

#define PROBE_T 2    // steps using dual-publish + probe before consensus

typedef __attribute__((ext_vector_type(8))) short bf16x8;
typedef __attribute__((ext_vector_type(4))) float f32x4;
typedef unsigned long long ull;

__device__ __forceinline__ unsigned short f2bf(float f) {
    union { float f; unsigned u; } v; v.f = f;
    unsigned u = v.u;
    return (unsigned short)((u + 0x7FFFu + ((u >> 16) & 1u)) >> 16);  // RNE
}
__device__ __forceinline__ float bf2f(unsigned short u) {
    union { unsigned u; float f; } v; v.u = ((unsigned)u) << 16; return v.f;
}
__device__ __forceinline__ float sigf(float x) { return 1.0f / (1.0f + __expf(-x)); }
__device__ __forceinline__ float tanhfast(float x) { return 1.0f - 2.0f / (__expf(2.0f * x) + 1.0f); }

// ---------------- Prologue: pack weights into MFMA B-fragment layout ----------------
__global__ void pack_w1(const float* __restrict__ Wih, const float* __restrict__ Whh,
                        unsigned short* __restrict__ Bp) {
    int idx = blockIdx.x * blockDim.x + threadIdx.x;
    if (idx >= 2 * 64 * 9 * 64) return;
    int fl   = idx / (64 * 9 * 64);
    int rem  = idx % (64 * 9 * 64);
    int tile = rem / (9 * 64);
    int kk   = (rem / 64) % 9;
    int l    = rem & 63;
    int n    = tile * 16 + (l & 15);
    int k0   = kk * 32 + (l >> 4) * 8;
    unsigned short* dst = Bp + (size_t)idx * 8;
#pragma unroll
    for (int j = 0; j < 8; ++j) {
        int k = k0 + j;
        float v = (k < NH) ? Whh[((size_t)fl * G4 + n) * NH + k]
                           : Wih[((size_t)fl * G4 + n) * NIN + (k - NH)];
        dst[j] = f2bf(v);
    }
}

__global__ void pack_w2(const float* __restrict__ Wih, const float* __restrict__ Whh,
                        unsigned short* __restrict__ Bp) {
    int idx = blockIdx.x * blockDim.x + threadIdx.x;
    if (idx >= 64 * 16 * 64) return;
    int tile = idx / (16 * 64);
    int kk   = (idx / 64) % 16;
    int l    = idx & 63;
    int n    = tile * 16 + (l & 15);
    int k0   = kk * 32 + (l >> 4) * 8;
    unsigned short* dst = Bp + (size_t)idx * 8;
#pragma unroll
    for (int j = 0; j < 8; ++j) {
        int k = k0 + j;
        float v = (k < NH) ? Whh[(size_t)n * NH + k] : Wih[(size_t)n * NH + (k - NH)];
        dst[j] = f2bf(v);
    }
}

// ---------------- Layer 1: 2 blocks/seq (fan-in 1), R7 protocol, 2 tiles/wave ----------------
// bid = j*32 + s (j=0,1) -> both blocks of seq s on XCD s%8 (heuristic; runtime-validated).
// Block j owns cols j*128..j*128+127 (32 gate-tiles). Wave w (16): ct=w&7, gp=w>>3;
// tiles TA=(2gp)*16+j*8+ct (gate 2gp), TB=(2gp+1)*16+j*8+ct (gate 2gp+1).
// Weights: wregA[9]+wregB[9] = 72 VGPR, ALL literal indices (rule #20). Total ~110 VGPR.
// Exchange: tagged words {bf16<<16|t+1}, parity dbuf; probe->consensus->pure-F, S fallback.
#define STRA 320                   // Ash row stride in ushorts; 640B = 5*128B
#define ASH_BYTES (NB * STRA * 2)  // 10240 per buffer

__device__ __forceinline__ unsigned aoff(int row, int col) {  // swizzled byte offset
    return (((unsigned)(row * STRA + col)) * 2u) ^ (((unsigned)row & 7u) << 4);
}

__global__ __launch_bounds__(1024, 4) void lstm_layer1(
    const float* __restrict__ x, const int* __restrict__ flags,
    const float* __restrict__ bih, const float* __restrict__ bhh,
    const unsigned short* __restrict__ Bp_all,
    unsigned short* __restrict__ h1bf,
    unsigned* __restrict__ hxS,    // [NSEQ][2][NB][256] tagged uints (MALL path)
    unsigned* __restrict__ hxF,    // [NSEQ][2][NB][256] tagged uints (L2 path)
    unsigned* __restrict__ vslot)  // [NSEQ][4] verdicts (j=0,1 used)
{
    __shared__ __align__(16) unsigned char Ash[2][ASH_BYTES];  // [h(256)|x(32)] swizzled
    __shared__ float gate[4][128][17];                         // [gate][local col][batch]
    __shared__ int s_fail, s_groupF;

    const int bid = blockIdx.x;
    const int s   = bid & 31;
    const int j   = bid >> 5;       // 0..1
    const int tid = threadIdx.x;
    const int w = tid >> 6, l = tid & 63, lr = l & 15, kg = l >> 4;
    const int ct = w & 7, gp = w >> 3;           // col-tile 0..7, gate-pair 0..1
    const int TA = (2 * gp) * 16 + j * 8 + ct;   // tile for gate 2gp
    const int TB = (2 * gp + 1) * 16 + j * 8 + ct;
    const int lc = ct * 16 + lr;                 // local col of this lane's tile rows
    const int fl = flags[s];
    const unsigned short* Bp = Bp_all + (size_t)fl * (64 * 9 * 64 * 8);
    const int rembase = (1 - j) << 7;            // remote col base (128 cols)

    bf16x8 wregA[9], wregB[9];
#pragma unroll
    for (int kk = 0; kk < 9; ++kk) {
        wregA[kk] = *(const bf16x8*)(Bp + ((size_t)(TA * 9 + kk) * 64 + l) * 8);
        wregB[kk] = *(const bf16x8*)(Bp + ((size_t)(TB * 9 + kk) * 64 + l) * 8);
    }
    const float biasA = bih[fl * G4 + TA * 16 + lr] + bhh[fl * G4 + TA * 16 + lr];
    const float biasB = bih[fl * G4 + TB * 16 + lr] + bhh[fl * G4 + TB * 16 + lr];

    // epilogue mapping: thread -> (batch pb, local cols lc0, lc0+1)
    const int pb  = tid >> 6;
    const int lc0 = (tid & 63) * 2;
    float cst0 = 0.f, cst1 = 0.f;
    // readback mapping: (batch rb, remote col pair rc0)
    const int rb  = tid >> 6;
    const int rc0 = rembase + (tid & 63) * 2;
    const int xb = tid >> 5, xk = tid & 31;      // x staging (tid < 512)
    int mode = 0;        // sticky per-thread: 0 probe, 1 F, 2 S
    bool groupF = false;

    unsigned* hxSs = hxS + (size_t)s * (2 * NB * 256);
    unsigned* hxFs = hxF + (size_t)s * (2 * NB * 256);

    if (tid == 0) { s_fail = 0; s_groupF = 0; }
    for (int i = tid * 4; i < 2 * ASH_BYTES; i += 1024 * 4)
        *(unsigned*)(&Ash[0][0] + i) = 0u;
    __syncthreads();
    if (tid < NB * NIN)
        *(unsigned short*)(&Ash[0][0] + aoff(xb, NH + xk)) =
            f2bf(x[(((size_t)s * SEQLEN) * NB + xb) * NIN + xk]);
    __syncthreads();

    for (int t = 0; t < SEQLEN; ++t) {
        const int cur = t & 1, nxt = cur ^ 1;
        float xpre = 0.f;
        if (t + 1 < SEQLEN && tid < NB * NIN)
            xpre = x[(((size_t)s * SEQLEN + t + 1) * NB + xb) * NIN + xk];

        // 18 MFMA: two independent chains (gates 2gp, 2gp+1) sharing A-fragment reads
        f32x4 accA = {biasA, biasA, biasA, biasA};
        f32x4 accB = {biasB, biasB, biasB, biasB};
#pragma unroll
        for (int kk = 0; kk < 9; ++kk) {
            bf16x8 a = *(const bf16x8*)(Ash[cur] + aoff(lr, kk * 32 + kg * 8));
            accA = __builtin_amdgcn_mfma_f32_16x16x32_bf16(a, wregA[kk], accA, 0, 0, 0);
            accB = __builtin_amdgcn_mfma_f32_16x16x32_bf16(a, wregB[kk], accB, 0, 0, 0);
        }
#pragma unroll
        for (int r = 0; r < 4; ++r) {
            gate[2 * gp    ][lc][kg * 4 + r] = accA[r];
            gate[2 * gp + 1][lc][kg * 4 + r] = accB[r];
        }
        __syncthreads();  // B1: gates ready, all Ash[cur] reads done

        // epilogue: thread owns (batch pb, local cols lc0, lc0+1)
        unsigned short hb0, hb1;
        {
            float ig = gate[0][lc0][pb], fg = gate[1][lc0][pb];
            float gg = gate[2][lc0][pb], og = gate[3][lc0][pb];
            float cn = sigf(fg) * cst0 + sigf(ig) * tanhfast(gg);
            cst0 = cn;
            hb0 = f2bf(sigf(og) * tanhfast(cn));
        }
        {
            float ig = gate[0][lc0 + 1][pb], fg = gate[1][lc0 + 1][pb];
            float gg = gate[2][lc0 + 1][pb], og = gate[3][lc0 + 1][pb];
            float cn = sigf(fg) * cst1 + sigf(ig) * tanhfast(gg);
            cst1 = cn;
            hb1 = f2bf(sigf(og) * tanhfast(cn));
        }
        const int gcol = (j << 7) + lc0;  // global col of pair

        if (t == SEQLEN - 1) {
            h1bf[((size_t)s * NB + pb) * NH + gcol]     = hb0;
            h1bf[((size_t)s * NB + pb) * NH + gcol + 1] = hb1;
        } else {
            const unsigned tg = (unsigned)(t + 1);
            const unsigned w0 = ((unsigned)hb0 << 16) | tg;
            const unsigned w1 = ((unsigned)hb1 << 16) | tg;
            unsigned* rowF = hxFs + (size_t)(nxt * NB + pb) * 256;
            unsigned* rowS = hxSs + (size_t)(nxt * NB + pb) * 256;
            // own cols -> next Ash + fast publish (8B store, aligned)
            *(unsigned*)(Ash[nxt] + aoff(pb, gcol)) = (unsigned)hb0 | ((unsigned)hb1 << 16);
            *(ull*)&rowF[gcol] = ((ull)w1 << 32) | (ull)w0;
            if ((t < PROBE_T) || !groupF) {
                __hip_atomic_store(rowS + gcol,     w0, __ATOMIC_RELAXED, __HIP_MEMORY_SCOPE_AGENT);
                __hip_atomic_store(rowS + gcol + 1, w1, __ATOMIC_RELAXED, __HIP_MEMORY_SCOPE_AGENT);
            }
            // x(t+1) -> next Ash while posts are in flight
            if (tid < NB * NIN)
                *(unsigned short*)(Ash[nxt] + aoff(xb, NH + xk)) = f2bf(xpre);

            // readback: single peer, 2 words per thread (coalesced)
            unsigned* prF = hxFs + (size_t)(nxt * NB + rb) * 256;
            volatile const unsigned* F = prF;
            unsigned v0 = F[rc0], v1 = F[rc0 + 1];
            if (groupF) {
                while ((v0 & 0xFFFFu) != tg) v0 = F[rc0];
                while ((v1 & 0xFFFFu) != tg) v1 = F[rc0 + 1];
            } else {
                bool ok = false;
                if (mode != 2) {
                    int budget = (mode == 0) ? 300 : 4000;
                    while ((v0 & 0xFFFFu) != tg && budget-- > 0) v0 = F[rc0];
                    while ((v1 & 0xFFFFu) != tg && budget-- > 0) v1 = F[rc0 + 1];
                    ok = ((v0 & 0xFFFFu) == tg) && ((v1 & 0xFFFFu) == tg);
                    if (t >= PROBE_T) mode = ok ? 1 : 2;
                }
                if (!ok) {
                    if (t < PROBE_T) s_fail = 1;  // benign race, same value
                    const unsigned* Srow = hxSs + (size_t)(nxt * NB + rb) * 256;
                    do { v0 = __hip_atomic_load(Srow + rc0,     __ATOMIC_RELAXED, __HIP_MEMORY_SCOPE_AGENT); } while ((v0 & 0xFFFFu) != tg);
                    do { v1 = __hip_atomic_load(Srow + rc0 + 1, __ATOMIC_RELAXED, __HIP_MEMORY_SCOPE_AGENT); } while ((v1 & 0xFFFFu) != tg);
                }
            }
            *(unsigned*)(Ash[nxt] + aoff(rb, rc0)) = (v0 >> 16) | (v1 & 0xFFFF0000u);
            __syncthreads();  // B2: Ash[nxt] complete for step t+1

            if (t == PROBE_T - 1) {
                if (tid == 0) {
                    unsigned verdict = (s_fail == 0) ? 2u : 1u;
                    __hip_atomic_store(vslot + s * 4 + j, verdict,
                                       __ATOMIC_RELAXED, __HIP_MEMORY_SCOPE_AGENT);
                    unsigned a0, a1;
                    do {
                        a0 = __hip_atomic_load(vslot + s * 4 + 0, __ATOMIC_RELAXED, __HIP_MEMORY_SCOPE_AGENT);
                        a1 = __hip_atomic_load(vslot + s * 4 + 1, __ATOMIC_RELAXED, __HIP_MEMORY_SCOPE_AGENT);
                    } while (!(a0 && a1));
                    s_groupF = (a0 == 2u && a1 == 2u) ? 1 : 0;
                }
                __syncthreads();  // once per kernel
                groupF = (s_groupF != 0);
            }
        }
    }
}

// ---------------- Layer 2: 4 blocks (grid 32, bid%8==0 -> same XCD), 32-step scan ----------------
#define STRA2 520  // 512 data + 8 pad

__global__ __launch_bounds__(1024) void lstm_layer2(
    const unsigned short* __restrict__ h1bf,
    const float* __restrict__ bih2, const float* __restrict__ bhh2,
    const unsigned short* __restrict__ Bp2,
    const float* __restrict__ Wlin, const float* __restrict__ blin,
    float* __restrict__ out,
    unsigned* __restrict__ hx2S,   // [2][NB][256] tagged uints (MALL)
    unsigned* __restrict__ hx2F,   // [2][NB][256] tagged uints (L2)
    unsigned* __restrict__ vslot2) // [4]
{
    const int bid = blockIdx.x;
    if (bid & 7) return;
    const int j = bid >> 3;  // 0..3

    __shared__ __align__(16) unsigned short A_sh[NB * STRA2];  // [h2(256)|h1_s(256)]
    __shared__ float gate[4][64][17];
    __shared__ float red[NB * 16];
    __shared__ int s_fail, s_groupF;

    const int tid = threadIdx.x;
    const int w = tid >> 6, l = tid & 63, lr = l & 15, kg = l >> 4;
    const int g = w >> 2, cg = w & 3;
    const int tile = g * 16 + j * 4 + cg;

    bf16x8 wreg[16];
#pragma unroll
    for (int kk = 0; kk < 16; ++kk)
        wreg[kk] = *(const bf16x8*)(Bp2 + ((size_t)(tile * 16 + kk) * 64 + l) * 8);

    const int grow = tile * 16 + lr;
    const float bias = bih2[grow] + bhh2[grow];
    const int pb = tid >> 6, pc = tid & 63;          // epilogue: 1 col per thread
    float cst = 0.f;
    int mode = 0;
    bool groupF = false;
    const int rb = tid >> 6, rc4 = (tid & 63) * 4;   // h1 staging: 4 cols per thread
    const int q0 = (((j + 1) & 3) << 6) + pc;
    const int q1 = (((j + 2) & 3) << 6) + pc;
    const int q2 = (((j + 3) & 3) << 6) + pc;

    if (tid == 0) { s_fail = 0; s_groupF = 0; }
    for (int i = tid; i < NB * NH; i += 1024)
        A_sh[(i >> 8) * STRA2 + (i & 255)] = 0;
    *(ushort4*)&A_sh[rb * STRA2 + NH + rc4] = *(const ushort4*)&h1bf[(size_t)rb * NH + rc4];
    __syncthreads();

    for (int sq = 0; sq < NSEQ; ++sq) {
        ushort4 pre = {0, 0, 0, 0};
        if (sq + 1 < NSEQ)
            pre = *(const ushort4*)&h1bf[((size_t)(sq + 1) * NB + rb) * NH + rc4];

        f32x4 acc = {bias, bias, bias, bias};
        f32x4 accB = {0.f, 0.f, 0.f, 0.f};
#pragma unroll
        for (int kk = 0; kk < 8; ++kk) {
            bf16x8 a = *(const bf16x8*)&A_sh[lr * STRA2 + kk * 32 + kg * 8];
            acc = __builtin_amdgcn_mfma_f32_16x16x32_bf16(a, wreg[kk], acc, 0, 0, 0);
        }
#pragma unroll
        for (int kk = 8; kk < 16; ++kk) {
            bf16x8 a = *(const bf16x8*)&A_sh[lr * STRA2 + kk * 32 + kg * 8];
            accB = __builtin_amdgcn_mfma_f32_16x16x32_bf16(a, wreg[kk], accB, 0, 0, 0);
        }
#pragma unroll
        for (int r = 0; r < 4; ++r)
            gate[g][cg * 16 + lr][kg * 4 + r] = acc[r] + accB[r];
        __syncthreads();  // B1

        const unsigned tg = (unsigned)(sq + 1);
        const size_t ro = (size_t)((((sq + 1) & 1) * NB + pb) << 8);
        unsigned* rowF = hx2F + ro;
        unsigned* rowS = hx2S + ro;
        volatile const unsigned* F = rowF;
        {
            float ig = gate[0][pc][pb], fg = gate[1][pc][pb];
            float gg = gate[2][pc][pb], og = gate[3][pc][pb];
            float cn = sigf(fg) * cst + sigf(ig) * tanhfast(gg);
            cst = cn;
            float h = sigf(og) * tanhfast(cn);
            unsigned word = ((unsigned)f2bf(h) << 16) | tg;
            A_sh[pb * STRA2 + (j << 6) + pc] = (unsigned short)(word >> 16);
            rowF[(j << 6) + pc] = word;
            if ((sq < PROBE_T) || !groupF)
                __hip_atomic_store(rowS + (j << 6) + pc, word,
                                   __ATOMIC_RELAXED, __HIP_MEMORY_SCOPE_AGENT);
        }
        unsigned v0 = F[q0], v1 = F[q1], v2 = F[q2];
        if (sq + 1 < NSEQ)
            *(ushort4*)&A_sh[rb * STRA2 + NH + rc4] = pre;

        if (groupF) {
            while ((v0 & 0xFFFFu) != tg) v0 = F[q0];
            while ((v1 & 0xFFFFu) != tg) v1 = F[q1];
            while ((v2 & 0xFFFFu) != tg) v2 = F[q2];
        } else {
            bool ok = false;
            if (mode != 2) {
                int budget = (mode == 0) ? 300 : 4000;
                while ((v0 & 0xFFFFu) != tg && budget-- > 0) v0 = F[q0];
                while ((v1 & 0xFFFFu) != tg && budget-- > 0) v1 = F[q1];
                while ((v2 & 0xFFFFu) != tg && budget-- > 0) v2 = F[q2];
                ok = ((v0 & 0xFFFFu) == tg) && ((v1 & 0xFFFFu) == tg) && ((v2 & 0xFFFFu) == tg);
                if (sq >= PROBE_T) mode = ok ? 1 : 2;
            }
            if (!ok) {
                if (sq < PROBE_T) s_fail = 1;
                do { v0 = __hip_atomic_load(rowS + q0, __ATOMIC_RELAXED, __HIP_MEMORY_SCOPE_AGENT); } while ((v0 & 0xFFFFu) != tg);
                do { v1 = __hip_atomic_load(rowS + q1, __ATOMIC_RELAXED, __HIP_MEMORY_SCOPE_AGENT); } while ((v1 & 0xFFFFu) != tg);
                do { v2 = __hip_atomic_load(rowS + q2, __ATOMIC_RELAXED, __HIP_MEMORY_SCOPE_AGENT); } while ((v2 & 0xFFFFu) != tg);
            }
        }
        A_sh[pb * STRA2 + q0] = (unsigned short)(v0 >> 16);
        A_sh[pb * STRA2 + q1] = (unsigned short)(v1 >> 16);
        A_sh[pb * STRA2 + q2] = (unsigned short)(v2 >> 16);
        __syncthreads();  // B2

        if (sq == PROBE_T - 1) {
            if (tid == 0) {
                unsigned verdict = (s_fail == 0) ? 2u : 1u;
                __hip_atomic_store(vslot2 + j, verdict, __ATOMIC_RELAXED, __HIP_MEMORY_SCOPE_AGENT);
                unsigned a0, a1, a2, a3;
                do {
                    a0 = __hip_atomic_load(vslot2 + 0, __ATOMIC_RELAXED, __HIP_MEMORY_SCOPE_AGENT);
                    a1 = __hip_atomic_load(vslot2 + 1, __ATOMIC_RELAXED, __HIP_MEMORY_SCOPE_AGENT);
                    a2 = __hip_atomic_load(vslot2 + 2, __ATOMIC_RELAXED, __HIP_MEMORY_SCOPE_AGENT);
                    a3 = __hip_atomic_load(vslot2 + 3, __ATOMIC_RELAXED, __HIP_MEMORY_SCOPE_AGENT);
                } while (!(a0 && a1 && a2 && a3));
                s_groupF = (a0 == 2u && a1 == 2u && a2 == 2u && a3 == 2u) ? 1 : 0;
            }
            __syncthreads();
            groupF = (s_groupF != 0);
        }
    }

    // final linear + sigmoid, block 0 (A_sh h-part holds full final h2)
    if (j == 0) {
        if (tid < 256) {
            int b = tid >> 4, kc = tid & 15;
            float pacc = 0.f;
#pragma unroll
            for (int k = 0; k < 16; ++k)
                pacc += bf2f(A_sh[b * STRA2 + kc * 16 + k]) * Wlin[kc * 16 + k];
            red[b * 16 + kc] = pacc;
        }
        __syncthreads();
        if (tid < 16) {
            float ssum = blin[0];
#pragma unroll
            for (int kc = 0; kc < 16; ++kc) ssum += red[tid * 16 + kc];
            out[tid] = 1.0f / (1.0f + __expf(-ssum));
        }
    }
}

// ---------------- host ----------------
extern "C" void kernel_launch(void* const* d_in, const int* in_sizes, int n_in,
                              void* d_out, int out_size, void* d_ws, size_t ws_size,
                              hipStream_t stream) {
    const float* x    = (const float*)d_in[0];
    const int*   flg  = (const int*)d_in[1];
    const float* Wih1 = (const float*)d_in[2];
    const float* Whh1 = (const float*)d_in[3];
    const float* bih1 = (const float*)d_in[4];
    const float* bhh1 = (const float*)d_in[5];
    const float* Wih2 = (const float*)d_in[6];
    const float* Whh2 = (const float*)d_in[7];
    const float* bih2 = (const float*)d_in[8];
    const float* bhh2 = (const float*)d_in[9];
    const float* Wlin = (const float*)d_in[10];
    const float* blin = (const float*)d_in[11];
    float* out = (float*)d_out;

    // workspace layout (ushort units; uint regions 4B-aligned)
    unsigned short* ws   = (unsigned short*)d_ws;
    unsigned short* Bp1  = ws;                       // 2*64*9*64*8  = 589824 ush
    unsigned short* Bp2  = Bp1 + 589824;             // 64*16*64*8   = 524288 ush
    unsigned short* h1bf = Bp2 + 524288;             // 32*16*256    = 131072 ush
    unsigned*       hxS1 = (unsigned*)(h1bf + 131072);  // 262144 uints
    unsigned*       hxF1 = hxS1 + 262144;               // 262144 uints
    unsigned*       hx2S = hxF1 + 262144;               // 8192 uints
    unsigned*       hx2F = hx2S + 8192;                 // 8192 uints
    unsigned*       vs1  = hx2F + 8192;                 // 128 uints
    unsigned*       vs2  = vs1 + 128;                   // 4 uints
    // total ~= 4.65 MB

    // invalidate all exchange tags + verdicts for this launch (captured in graph)
    (void)hipMemsetAsync(hxS1, 0, (size_t)(262144 * 2 + 8192 * 2 + 132) * 4, stream);

    pack_w1<<<dim3(288), dim3(256), 0, stream>>>(Wih1, Whh1, Bp1);
    pack_w2<<<dim3(256), dim3(256), 0, stream>>>(Wih2, Whh2, Bp2);
    lstm_layer1<<<dim3(64), dim3(1024), 0, stream>>>(x, flg, bih1, bhh1, Bp1, h1bf,
                                                     hxS1, hxF1, vs1);
    lstm_layer2<<<dim3(32), dim3(1024), 0, stream>>>(h1bf, bih2, bhh2, Bp2, Wlin, blin, out,
                                                     hx2S, hx2F, vs2);
}

// Round 14
// 577.421 us; speedup vs baseline: 15.3581x; 1.3340x over previous
//
#include <hip/hip_runtime.h>
#include <hip/hip_bf16.h>

// Sizes from the reference
#define NSEQ   32
#define SEQLEN 256
#define NB     16    // batch
#define NIN    32
#define NH     256
#define G4     1024  // 4*H

#define PROBE_T 2    // steps using dual-publish + probe before consensus

typedef __attribute__((ext_vector_type(8))) short bf16x8;
typedef __attribute__((ext_vector_type(4))) float f32x4;
typedef unsigned long long ull;

__device__ __forceinline__ unsigned short f2bf(float f) {
    union { float f; unsigned u; } v; v.f = f;
    unsigned u = v.u;
    return (unsigned short)((u + 0x7FFFu + ((u >> 16) & 1u)) >> 16);  // RNE
}
__device__ __forceinline__ float bf2f(unsigned short u) {
    union { unsigned u; float f; } v; v.u = ((unsigned)u) << 16; return v.f;
}
__device__ __forceinline__ float sigf(float x) { return 1.0f / (1.0f + __expf(-x)); }
__device__ __forceinline__ float tanhfast(float x) { return 1.0f - 2.0f / (__expf(2.0f * x) + 1.0f); }

// ---------------- Prologue: pack weights into MFMA B-fragment layout ----------------
__global__ void pack_w1(const float* __restrict__ Wih, const float* __restrict__ Whh,
                        unsigned short* __restrict__ Bp) {
    int idx = blockIdx.x * blockDim.x + threadIdx.x;
    if (idx >= 2 * 64 * 9 * 64) return;
    int fl   = idx / (64 * 9 * 64);
    int rem  = idx % (64 * 9 * 64);
    int tile = rem / (9 * 64);
    int kk   = (rem / 64) % 9;
    int l    = rem & 63;
    int n    = tile * 16 + (l & 15);
    int k0   = kk * 32 + (l >> 4) * 8;
    unsigned short* dst = Bp + (size_t)idx * 8;
#pragma unroll
    for (int j = 0; j < 8; ++j) {
        int k = k0 + j;
        float v = (k < NH) ? Whh[((size_t)fl * G4 + n) * NH + k]
                           : Wih[((size_t)fl * G4 + n) * NIN + (k - NH)];
        dst[j] = f2bf(v);
    }
}

__global__ void pack_w2(const float* __restrict__ Wih, const float* __restrict__ Whh,
                        unsigned short* __restrict__ Bp) {
    int idx = blockIdx.x * blockDim.x + threadIdx.x;
    if (idx >= 64 * 16 * 64) return;
    int tile = idx / (16 * 64);
    int kk   = (idx / 64) % 16;
    int l    = idx & 63;
    int n    = tile * 16 + (l & 15);
    int k0   = kk * 32 + (l >> 4) * 8;
    unsigned short* dst = Bp + (size_t)idx * 8;
#pragma unroll
    for (int j = 0; j < 8; ++j) {
        int k = k0 + j;
        float v = (k < NH) ? Whh[(size_t)n * NH + k] : Wih[(size_t)n * NH + (k - NH)];
        dst[j] = f2bf(v);
    }
}

// ---------------- Layer 1: 4 blocks/seq, consensus-gated L2 exchange ----------------
// bid = j*32 + s -> 4 blocks of seq s on XCD s%8 (heuristic; validated at runtime).
// t < PROBE_T: dual publish (F: plain store->L2, S: AGENT atomic->MALL), probe F w/ budget,
//              fall back to S, record failures. After t=PROBE_T-1: 4 blocks exchange
//              verdicts via MALL (guaranteed); if all-F -> pure-F forever (placement is
//              static per launch), else keep dual-publish + per-thread sticky mode.
#define STRA 320                   // Ash row stride in ushorts; 640B = 5*128B
#define ASH_BYTES (NB * STRA * 2)  // 10240

__device__ __forceinline__ unsigned aoff(int row, int col) {  // swizzled byte offset
    return (((unsigned)(row * STRA + col)) * 2u) ^ (((unsigned)row & 7u) << 4);
}

__global__ __launch_bounds__(1024) void lstm_layer1(
    const float* __restrict__ x, const int* __restrict__ flags,
    const float* __restrict__ bih, const float* __restrict__ bhh,
    const unsigned short* __restrict__ Bp_all,
    unsigned short* __restrict__ h1bf,
    unsigned* __restrict__ hxS,    // [NSEQ][2][NB][256] tagged uints (MALL path)
    unsigned* __restrict__ hxF,    // [NSEQ][2][NB][256] tagged uints (L2 path)
    unsigned* __restrict__ vslot)  // [NSEQ][4] verdicts
{
    __shared__ __align__(16) unsigned char Ash[ASH_BYTES];  // [h(256)|x(32)] swizzled
    __shared__ float gate[4][64][17];
    __shared__ int s_fail, s_groupF;

    const int bid = blockIdx.x;
    const int s   = bid & 31;
    const int j   = bid >> 5;
    const int tid = threadIdx.x;
    const int w = tid >> 6, l = tid & 63, lr = l & 15, kg = l >> 4;
    const int g = w >> 2, cg = w & 3;
    const int fl = flags[s];
    const int tile = g * 16 + j * 4 + cg;
    const unsigned short* Bp = Bp_all + (size_t)fl * (64 * 9 * 64 * 8);

    bf16x8 wreg[9];
#pragma unroll
    for (int kk = 0; kk < 9; ++kk)
        wreg[kk] = *(const bf16x8*)(Bp + ((size_t)(tile * 9 + kk) * 64 + l) * 8);

    const int grow = tile * 16 + lr;
    const float bias = bih[fl * G4 + grow] + bhh[fl * G4 + grow];

    const int pb = tid >> 6, pc = tid & 63;   // epilogue/post/readback: (batch, local col)
    const int o0 = (((j + 1) & 3) << 6) + pc; // the 3 peer column slots
    const int o1 = (((j + 2) & 3) << 6) + pc;
    const int o2 = (((j + 3) & 3) << 6) + pc;
    const int xb = tid >> 5, xk = tid & 31;   // x staging (tid < 512)
    float cst = 0.f;
    int mode = 0;       // sticky per-thread (non-consensus path): 0 probe, 1 F, 2 S
    bool groupF = false;

    unsigned* hxSs = hxS + (size_t)s * (2 * NB * 256);
    unsigned* hxFs = hxF + (size_t)s * (2 * NB * 256);

    if (tid == 0) { s_fail = 0; s_groupF = 0; }
    for (int i = tid * 4; i < ASH_BYTES; i += 1024 * 4)
        *(unsigned*)(Ash + i) = 0u;
    __syncthreads();
    if (tid < NB * NIN)
        *(unsigned short*)(Ash + aoff(xb, NH + xk)) =
            f2bf(x[(((size_t)s * SEQLEN) * NB + xb) * NIN + xk]);
    __syncthreads();

    for (int t = 0; t < SEQLEN; ++t) {
        float xpre = 0.f;
        if (t + 1 < SEQLEN && tid < NB * NIN)
            xpre = x[(((size_t)s * SEQLEN + t + 1) * NB + xb) * NIN + xk];

        // MFMA: two independent chains
        f32x4 acc = {bias, bias, bias, bias};
        f32x4 accB = {0.f, 0.f, 0.f, 0.f};
#pragma unroll
        for (int kk = 0; kk < 5; ++kk) {
            bf16x8 a = *(const bf16x8*)(Ash + aoff(lr, kk * 32 + kg * 8));
            acc = __builtin_amdgcn_mfma_f32_16x16x32_bf16(a, wreg[kk], acc, 0, 0, 0);
        }
#pragma unroll
        for (int kk = 5; kk < 9; ++kk) {
            bf16x8 a = *(const bf16x8*)(Ash + aoff(lr, kk * 32 + kg * 8));
            accB = __builtin_amdgcn_mfma_f32_16x16x32_bf16(a, wreg[kk], accB, 0, 0, 0);
        }
#pragma unroll
        for (int r = 0; r < 4; ++r)
            gate[g][cg * 16 + lr][kg * 4 + r] = acc[r] + accB[r];
        __syncthreads();  // B1: gates ready, all Ash reads of step t done

        // epilogue: 1 thread = 1 (batch, col)
        float ig = gate[0][pc][pb], fg = gate[1][pc][pb];
        float gg = gate[2][pc][pb], og = gate[3][pc][pb];
        float cn = sigf(fg) * cst + sigf(ig) * tanhfast(gg);
        cst = cn;
        float h = sigf(og) * tanhfast(cn);
        unsigned short hb = f2bf(h);
        *(unsigned short*)(Ash + aoff(pb, (j << 6) + pc)) = hb;  // own col -> LDS

        if (t == SEQLEN - 1) {
            h1bf[((size_t)s * NB + pb) * NH + (j << 6) + pc] = hb;
        } else {
            const unsigned tg = (unsigned)(t + 1);
            const unsigned word = ((unsigned)hb << 16) | tg;
            const size_t ro = (size_t)((((t + 1) & 1) * NB + pb) << 8);
            unsigned* rowF = hxFs + ro;
            unsigned* rowS = hxSs + ro;
            volatile const unsigned* F = rowF;

            rowF[(j << 6) + pc] = word;                     // fast publish (local L2)
            const bool pubS = (t < PROBE_T) || !groupF;
            if (pubS)
                __hip_atomic_store(rowS + (j << 6) + pc, word,
                                   __ATOMIC_RELAXED, __HIP_MEMORY_SCOPE_AGENT);
            // issue initial F loads early, then overlap with x staging
            unsigned v0 = F[o0], v1 = F[o1], v2 = F[o2];
            if (tid < NB * NIN)
                *(unsigned short*)(Ash + aoff(xb, NH + xk)) = f2bf(xpre);

            if (groupF) {
                // consensus pure-F: placement static -> F always delivers
                while ((v0 & 0xFFFFu) != tg) v0 = F[o0];
                while ((v1 & 0xFFFFu) != tg) v1 = F[o1];
                while ((v2 & 0xFFFFu) != tg) v2 = F[o2];
            } else {
                bool ok = false;
                if (mode != 2) {
                    int budget = (mode == 0) ? 300 : 4000;
                    while ((v0 & 0xFFFFu) != tg && budget-- > 0) v0 = F[o0];
                    while ((v1 & 0xFFFFu) != tg && budget-- > 0) v1 = F[o1];
                    while ((v2 & 0xFFFFu) != tg && budget-- > 0) v2 = F[o2];
                    ok = ((v0 & 0xFFFFu) == tg) && ((v1 & 0xFFFFu) == tg) && ((v2 & 0xFFFFu) == tg);
                    if (t >= PROBE_T) mode = ok ? 1 : 2;
                }
                if (!ok) {  // safe path: MALL, guaranteed to arrive
                    if (t < PROBE_T) s_fail = 1;  // benign race, same value
                    v0 = __hip_atomic_load(rowS + o0, __ATOMIC_RELAXED, __HIP_MEMORY_SCOPE_AGENT);
                    v1 = __hip_atomic_load(rowS + o1, __ATOMIC_RELAXED, __HIP_MEMORY_SCOPE_AGENT);
                    v2 = __hip_atomic_load(rowS + o2, __ATOMIC_RELAXED, __HIP_MEMORY_SCOPE_AGENT);
                    while ((v0 & 0xFFFFu) != tg)
                        v0 = __hip_atomic_load(rowS + o0, __ATOMIC_RELAXED, __HIP_MEMORY_SCOPE_AGENT);
                    while ((v1 & 0xFFFFu) != tg)
                        v1 = __hip_atomic_load(rowS + o1, __ATOMIC_RELAXED, __HIP_MEMORY_SCOPE_AGENT);
                    while ((v2 & 0xFFFFu) != tg)
                        v2 = __hip_atomic_load(rowS + o2, __ATOMIC_RELAXED, __HIP_MEMORY_SCOPE_AGENT);
                }
            }
            *(unsigned short*)(Ash + aoff(pb, o0)) = (unsigned short)(v0 >> 16);
            *(unsigned short*)(Ash + aoff(pb, o1)) = (unsigned short)(v1 >> 16);
            *(unsigned short*)(Ash + aoff(pb, o2)) = (unsigned short)(v2 >> 16);
            __syncthreads();  // B2: Ash complete for step t+1

            if (t == PROBE_T - 1) {
                // group consensus via MALL (guaranteed delivery)
                if (tid == 0) {
                    unsigned verdict = (s_fail == 0) ? 2u : 1u;
                    __hip_atomic_store(vslot + s * 4 + j, verdict,
                                       __ATOMIC_RELAXED, __HIP_MEMORY_SCOPE_AGENT);
                    unsigned a0, a1, a2, a3;
                    do {
                        a0 = __hip_atomic_load(vslot + s * 4 + 0, __ATOMIC_RELAXED, __HIP_MEMORY_SCOPE_AGENT);
                        a1 = __hip_atomic_load(vslot + s * 4 + 1, __ATOMIC_RELAXED, __HIP_MEMORY_SCOPE_AGENT);
                        a2 = __hip_atomic_load(vslot + s * 4 + 2, __ATOMIC_RELAXED, __HIP_MEMORY_SCOPE_AGENT);
                        a3 = __hip_atomic_load(vslot + s * 4 + 3, __ATOMIC_RELAXED, __HIP_MEMORY_SCOPE_AGENT);
                    } while (!(a0 && a1 && a2 && a3));
                    s_groupF = (a0 == 2u && a1 == 2u && a2 == 2u && a3 == 2u) ? 1 : 0;
                }
                __syncthreads();  // B3 (once per kernel)
                groupF = (s_groupF != 0);
            }
        }
    }
}

// ---------------- Layer 2: 4 blocks (grid 32, bid%8==0 -> same XCD), 32-step scan ----------------
#define STRA2 520  // 512 data + 8 pad

__global__ __launch_bounds__(1024) void lstm_layer2(
    const unsigned short* __restrict__ h1bf,
    const float* __restrict__ bih2, const float* __restrict__ bhh2,
    const unsigned short* __restrict__ Bp2,
    const float* __restrict__ Wlin, const float* __restrict__ blin,
    float* __restrict__ out,
    unsigned* __restrict__ hx2S,   // [2][NB][256] tagged uints (MALL)
    unsigned* __restrict__ hx2F,   // [2][NB][256] tagged uints (L2)
    unsigned* __restrict__ vslot2) // [4]
{
    const int bid = blockIdx.x;
    if (bid & 7) return;
    const int j = bid >> 3;  // 0..3

    __shared__ __align__(16) unsigned short A_sh[NB * STRA2];  // [h2(256)|h1_s(256)]
    __shared__ float gate[4][64][17];
    __shared__ float red[NB * 16];
    __shared__ int s_fail, s_groupF;

    const int tid = threadIdx.x;
    const int w = tid >> 6, l = tid & 63, lr = l & 15, kg = l >> 4;
    const int g = w >> 2, cg = w & 3;
    const int tile = g * 16 + j * 4 + cg;

    bf16x8 wreg[16];
#pragma unroll
    for (int kk = 0; kk < 16; ++kk)
        wreg[kk] = *(const bf16x8*)(Bp2 + ((size_t)(tile * 16 + kk) * 64 + l) * 8);

    const int grow = tile * 16 + lr;
    const float bias = bih2[grow] + bhh2[grow];
    const int pb = tid >> 6, pc = tid & 63;          // epilogue: 1 col per thread
    float cst = 0.f;
    int mode = 0;
    bool groupF = false;
    const int rb = tid >> 6, rc4 = (tid & 63) * 4;   // h1 staging: 4 cols per thread
    const int q0 = (((j + 1) & 3) << 6) + pc;
    const int q1 = (((j + 2) & 3) << 6) + pc;
    const int q2 = (((j + 3) & 3) << 6) + pc;

    if (tid == 0) { s_fail = 0; s_groupF = 0; }
    for (int i = tid; i < NB * NH; i += 1024)
        A_sh[(i >> 8) * STRA2 + (i & 255)] = 0;
    *(ushort4*)&A_sh[rb * STRA2 + NH + rc4] = *(const ushort4*)&h1bf[(size_t)rb * NH + rc4];
    __syncthreads();

    for (int sq = 0; sq < NSEQ; ++sq) {
        ushort4 pre = {0, 0, 0, 0};
        if (sq + 1 < NSEQ)
            pre = *(const ushort4*)&h1bf[((size_t)(sq + 1) * NB + rb) * NH + rc4];

        f32x4 acc = {bias, bias, bias, bias};
        f32x4 accB = {0.f, 0.f, 0.f, 0.f};
#pragma unroll
        for (int kk = 0; kk < 8; ++kk) {
            bf16x8 a = *(const bf16x8*)&A_sh[lr * STRA2 + kk * 32 + kg * 8];
            acc = __builtin_amdgcn_mfma_f32_16x16x32_bf16(a, wreg[kk], acc, 0, 0, 0);
        }
#pragma unroll
        for (int kk = 8; kk < 16; ++kk) {
            bf16x8 a = *(const bf16x8*)&A_sh[lr * STRA2 + kk * 32 + kg * 8];
            accB = __builtin_amdgcn_mfma_f32_16x16x32_bf16(a, wreg[kk], accB, 0, 0, 0);
        }
#pragma unroll
        for (int r = 0; r < 4; ++r)
            gate[g][cg * 16 + lr][kg * 4 + r] = acc[r] + accB[r];
        __syncthreads();  // B1

        // epilogue + dual publish
        const unsigned tg = (unsigned)(sq + 1);
        const size_t ro = (size_t)((((sq + 1) & 1) * NB + pb) << 8);
        unsigned* rowF = hx2F + ro;
        unsigned* rowS = hx2S + ro;
        volatile const unsigned* F = rowF;
        {
            float ig = gate[0][pc][pb], fg = gate[1][pc][pb];
            float gg = gate[2][pc][pb], og = gate[3][pc][pb];
            float cn = sigf(fg) * cst + sigf(ig) * tanhfast(gg);
            cst = cn;
            float h = sigf(og) * tanhfast(cn);
            unsigned word = ((unsigned)f2bf(h) << 16) | tg;
            A_sh[pb * STRA2 + (j << 6) + pc] = (unsigned short)(word >> 16);
            rowF[(j << 6) + pc] = word;
            if ((sq < PROBE_T) || !groupF)
                __hip_atomic_store(rowS + (j << 6) + pc, word,
                                   __ATOMIC_RELAXED, __HIP_MEMORY_SCOPE_AGENT);
        }
        if (sq + 1 < NSEQ)
            *(ushort4*)&A_sh[rb * STRA2 + NH + rc4] = pre;

        // readback h2(sq+1): 3 peer cols, sticky fast/safe
        {
            unsigned v0, v1, v2;
            bool ok = false;
            if (mode != 2) {
                int budget = (mode == 0) ? 256 : 4000;
                v0 = F[q0]; v1 = F[q1]; v2 = F[q2];
                while ((v0 & 0xFFFFu) != tg && budget-- > 0) v0 = F[q0];
                while ((v1 & 0xFFFFu) != tg && budget-- > 0) v1 = F[q1];
                while ((v2 & 0xFFFFu) != tg && budget-- > 0) v2 = F[q2];
                ok = ((v0 & 0xFFFFu) == tg) && ((v1 & 0xFFFFu) == tg) && ((v2 & 0xFFFFu) == tg);
                if (!groupF && sq >= PROBE_T) mode = ok ? 1 : 2;
            }
            if (!ok) {
                if (sq < PROBE_T) s_fail = 1;
                v0 = __hip_atomic_load(rowS + q0, __ATOMIC_RELAXED, __HIP_MEMORY_SCOPE_AGENT);
                v1 = __hip_atomic_load(rowS + q1, __ATOMIC_RELAXED, __HIP_MEMORY_SCOPE_AGENT);
                v2 = __hip_atomic_load(rowS + q2, __ATOMIC_RELAXED, __HIP_MEMORY_SCOPE_AGENT);
                while ((v0 & 0xFFFFu) != tg)
                    v0 = __hip_atomic_load(rowS + q0, __ATOMIC_RELAXED, __HIP_MEMORY_SCOPE_AGENT);
                while ((v1 & 0xFFFFu) != tg)
                    v1 = __hip_atomic_load(rowS + q1, __ATOMIC_RELAXED, __HIP_MEMORY_SCOPE_AGENT);
                while ((v2 & 0xFFFFu) != tg)
                    v2 = __hip_atomic_load(rowS + q2, __ATOMIC_RELAXED, __HIP_MEMORY_SCOPE_AGENT);
            }
            A_sh[pb * STRA2 + q0] = (unsigned short)(v0 >> 16);
            A_sh[pb * STRA2 + q1] = (unsigned short)(v1 >> 16);
            A_sh[pb * STRA2 + q2] = (unsigned short)(v2 >> 16);
        }
        __syncthreads();  // B2

        if (sq == PROBE_T - 1) {
            if (tid == 0) {
                unsigned verdict = (s_fail == 0) ? 2u : 1u;
                __hip_atomic_store(vslot2 + j, verdict, __ATOMIC_RELAXED, __HIP_MEMORY_SCOPE_AGENT);
                unsigned a0, a1, a2, a3;
                do {
                    a0 = __hip_atomic_load(vslot2 + 0, __ATOMIC_RELAXED, __HIP_MEMORY_SCOPE_AGENT);
                    a1 = __hip_atomic_load(vslot2 + 1, __ATOMIC_RELAXED, __HIP_MEMORY_SCOPE_AGENT);
                    a2 = __hip_atomic_load(vslot2 + 2, __ATOMIC_RELAXED, __HIP_MEMORY_SCOPE_AGENT);
                    a3 = __hip_atomic_load(vslot2 + 3, __ATOMIC_RELAXED, __HIP_MEMORY_SCOPE_AGENT);
                } while (!(a0 && a1 && a2 && a3));
                s_groupF = (a0 == 2u && a1 == 2u && a2 == 2u && a3 == 2u) ? 1 : 0;
            }
            __syncthreads();
            groupF = (s_groupF != 0);
        }
    }

    // final linear + sigmoid, block 0 (A_sh h-part holds full final h2)
    if (j == 0) {
        if (tid < 256) {
            int b = tid >> 4, kc = tid & 15;
            float pacc = 0.f;
#pragma unroll
            for (int k = 0; k < 16; ++k)
                pacc += bf2f(A_sh[b * STRA2 + kc * 16 + k]) * Wlin[kc * 16 + k];
            red[b * 16 + kc] = pacc;
        }
        __syncthreads();
        if (tid < 16) {
            float ssum = blin[0];
#pragma unroll
            for (int kc = 0; kc < 16; ++kc) ssum += red[tid * 16 + kc];
            out[tid] = 1.0f / (1.0f + __expf(-ssum));
        }
    }
}

// ---------------- host ----------------
extern "C" void kernel_launch(void* const* d_in, const int* in_sizes, int n_in,
                              void* d_out, int out_size, void* d_ws, size_t ws_size,
                              hipStream_t stream) {
    const float* x    = (const float*)d_in[0];
    const int*   flg  = (const int*)d_in[1];
    const float* Wih1 = (const float*)d_in[2];
    const float* Whh1 = (const float*)d_in[3];
    const float* bih1 = (const float*)d_in[4];
    const float* bhh1 = (const float*)d_in[5];
    const float* Wih2 = (const float*)d_in[6];
    const float* Whh2 = (const float*)d_in[7];
    const float* bih2 = (const float*)d_in[8];
    const float* bhh2 = (const float*)d_in[9];
    const float* Wlin = (const float*)d_in[10];
    const float* blin = (const float*)d_in[11];
    float* out = (float*)d_out;

    // workspace layout (ushort units; uint regions 4B-aligned)
    unsigned short* ws   = (unsigned short*)d_ws;
    unsigned short* Bp1  = ws;                       // 2*64*9*64*8  = 589824 ush
    unsigned short* Bp2  = Bp1 + 589824;             // 64*16*64*8   = 524288 ush
    unsigned short* h1bf = Bp2 + 524288;             // 32*16*256    = 131072 ush
    unsigned*       hxS1 = (unsigned*)(h1bf + 131072);  // 262144 uints
    unsigned*       hxF1 = hxS1 + 262144;               // 262144 uints
    unsigned*       hx2S = hxF1 + 262144;               // 8192 uints
    unsigned*       hx2F = hx2S + 8192;                 // 8192 uints
    unsigned*       vs1  = hx2F + 8192;                 // 128 uints
    unsigned*       vs2  = vs1 + 128;                   // 4 uints
    // total ~= 4.65 MB

    // invalidate all exchange tags + verdicts for this launch (captured in graph)
    (void)hipMemsetAsync(hxS1, 0, (size_t)(262144 * 2 + 8192 * 2 + 132) * 4, stream);

    pack_w1<<<dim3(288), dim3(256), 0, stream>>>(Wih1, Whh1, Bp1);
    pack_w2<<<dim3(256), dim3(256), 0, stream>>>(Wih2, Whh2, Bp2);
    lstm_layer1<<<dim3(128), dim3(1024), 0, stream>>>(x, flg, bih1, bhh1, Bp1, h1bf,
                                                      hxS1, hxF1, vs1);
    lstm_layer2<<<dim3(32), dim3(1024), 0, stream>>>(h1bf, bih2, bhh2, Bp2, Wlin, blin, out,
                                                     hx2S, hx2F, vs2);
}